// Round 4
// baseline (221.946 us; speedup 1.0000x reference)
//
#include <hip/hip_runtime.h>
#include <hip/hip_bf16.h>
#include <math.h>

#define S 4096
#define D 512
#define H 8
#define DK 64
#define WIN 128

typedef __attribute__((ext_vector_type(8))) short bf16x8;
typedef __attribute__((ext_vector_type(4))) float f32x4;

__device__ __forceinline__ unsigned short f2bf(float f) {
    __hip_bfloat16 h = __float2bfloat16(f);
    return *(unsigned short*)&h;
}

// ---------------------------------------------------------------------------
// fp32 -> bf16 conversion (x). 8 elems/thread.
// ---------------------------------------------------------------------------
__global__ __launch_bounds__(256) void conv_bf16_kernel(
    const float* __restrict__ in, unsigned short* __restrict__ out, int n)
{
    const int i = (blockIdx.x * 256 + threadIdx.x) * 8;
    if (i >= n) return;
    float4 a = *(const float4*)&in[i];
    float4 b = *(const float4*)&in[i + 4];
    ushort4 o0 = {f2bf(a.x), f2bf(a.y), f2bf(a.z), f2bf(a.w)};
    ushort4 o1 = {f2bf(b.x), f2bf(b.y), f2bf(b.z), f2bf(b.w)};
    *(ushort4*)&out[i]     = o0;
    *(ushort4*)&out[i + 4] = o1;
}

// ---------------------------------------------------------------------------
// Zero-fill the out-of-band complement of attn. Per row i: float4-aligned
// prefix [0, start) and suffix [start+272, 4096), where
// start = (max(i-128,0)) & ~3. The band kernel writes [start, start+272).
// Each block: 8 rows of one head. Pure streaming float4 stores.
// ---------------------------------------------------------------------------
__global__ __launch_bounds__(256) void attn_fill_kernel(float* __restrict__ attn)
{
    const int bid = blockIdx.x;          // 0..4095
    const int h = bid >> 9;
    const int g = bid & 511;
    const float4 z = make_float4(0.f, 0.f, 0.f, 0.f);
    #pragma unroll 1
    for (int rr = 0; rr < 8; ++rr) {
        const int i = g * 8 + rr;
        float* rowp = attn + (size_t)h * S * S + (size_t)i * S;
        const int start = max(i - WIN, 0) & ~3;
        const int pre = start >> 2;                        // prefix float4 count
        const int sstart = start + 272;
        const int suf = (sstart < S) ? ((S - sstart) >> 2) : 0;
        const int tot = pre + suf;
        for (int idx = threadIdx.x; idx < tot; idx += 256) {
            const int col = (idx < pre) ? (idx << 2) : (sstart + ((idx - pre) << 2));
            *(float4*)&rowp[col] = z;
        }
    }
}

// ---------------------------------------------------------------------------
// MFMA GEMM: C[m][n] = sum_e A[m][e]*W[n][e] + bias[n]
// ---------------------------------------------------------------------------
__device__ __forceinline__ void mfma_gemm_body(
    const unsigned short* __restrict__ A,
    const float* __restrict__ W,
    const float* __restrict__ bias,
    float* __restrict__ C,
    unsigned short* __restrict__ CB)
{
    __shared__ unsigned short Bs[64][520];

    const int tid  = threadIdx.x;
    const int m0   = blockIdx.x * 128;
    const int n0   = blockIdx.y * 64;
    const int wv   = tid >> 6;
    const int lane = tid & 63;
    const int l16  = lane & 15;
    const int klo  = (lane >> 4) * 8;

    #pragma unroll
    for (int it = 0; it < 16; ++it) {
        const int c   = tid + it * 256;
        const int row = c >> 6;
        const int kc  = (c & 63) * 8;
        const float* src = &W[(size_t)(n0 + row) * 512 + kc];
        float4 a = *(const float4*)&src[0];
        float4 b = *(const float4*)&src[4];
        ushort4 o0 = {f2bf(a.x), f2bf(a.y), f2bf(a.z), f2bf(a.w)};
        ushort4 o1 = {f2bf(b.x), f2bf(b.y), f2bf(b.z), f2bf(b.w)};
        *(ushort4*)&Bs[row][kc]     = o0;
        *(ushort4*)&Bs[row][kc + 4] = o1;
    }
    __syncthreads();

    const unsigned short* arow0 = &A[(size_t)(m0 + wv * 32 + l16) * 512 + klo];
    const unsigned short* arow1 = arow0 + 16 * 512;

    f32x4 acc[2][4];
    #pragma unroll
    for (int r = 0; r < 2; ++r)
        #pragma unroll
        for (int nf = 0; nf < 4; ++nf)
            acc[r][nf] = (f32x4){0.f, 0.f, 0.f, 0.f};

    #pragma unroll 4
    for (int kb = 0; kb < 512; kb += 32) {
        bf16x8 a0 = *(const bf16x8*)&arow0[kb];
        bf16x8 a1 = *(const bf16x8*)&arow1[kb];
        #pragma unroll
        for (int nf = 0; nf < 4; ++nf) {
            bf16x8 b = *(const bf16x8*)&Bs[nf * 16 + l16][kb + klo];
            acc[0][nf] = __builtin_amdgcn_mfma_f32_16x16x32_bf16(a0, b, acc[0][nf], 0, 0, 0);
            acc[1][nf] = __builtin_amdgcn_mfma_f32_16x16x32_bf16(a1, b, acc[1][nf], 0, 0, 0);
        }
    }

    const int r0 = (lane >> 4) * 4;
    #pragma unroll
    for (int r = 0; r < 2; ++r) {
        #pragma unroll
        for (int nf = 0; nf < 4; ++nf) {
            const int col = n0 + nf * 16 + l16;
            const float bb = bias[col];
            #pragma unroll
            for (int vv = 0; vv < 4; ++vv) {
                const int row = m0 + wv * 32 + r * 16 + r0 + vv;
                const float val = acc[r][nf][vv] + bb;
                if (C)  C [(size_t)row * 512 + col] = val;
                if (CB) CB[(size_t)row * 512 + col] = f2bf(val);
            }
        }
    }
}

__global__ __launch_bounds__(256) void proj3_kernel(
    const unsigned short* __restrict__ xb,
    const float* __restrict__ wq, const float* __restrict__ bq,
    const float* __restrict__ wk, const float* __restrict__ bk,
    const float* __restrict__ wv, const float* __restrict__ bv,
    float* __restrict__ q, float* __restrict__ k, float* __restrict__ v)
{
    const float* W; const float* b; float* C;
    if (blockIdx.z == 0)      { W = wq; b = bq; C = q; }
    else if (blockIdx.z == 1) { W = wk; b = bk; C = k; }
    else                      { W = wv; b = bv; C = v; }
    mfma_gemm_body(xb, W, b, C, nullptr);
}

__global__ __launch_bounds__(256) void outproj_kernel(
    const unsigned short* __restrict__ ctxb,
    const float* __restrict__ wo, const float* __restrict__ bo,
    float* __restrict__ out)
{
    mfma_gemm_body(ctxb, wo, bo, out, nullptr);
}

// ---------------------------------------------------------------------------
// Band attention weights: scores -> softmax -> write ONLY the 272-col aligned
// band window per row. One block per (64-query block, head).
// ---------------------------------------------------------------------------
__global__ __launch_bounds__(256) void band_attn_kernel(
    const float* __restrict__ q, const float* __restrict__ k,
    float* __restrict__ attn)
{
    __shared__ float Qs[64][68];    // transposed: Qs[d][row]
    __shared__ float Ks[64][68];    // transposed: Ks[d][col]
    __shared__ float P[64][336];    // band scores, local window coords
    __shared__ float rinvs[64];

    const int tid = threadIdx.x;
    const int h  = blockIdx.y;
    const int q0 = blockIdx.x * 64;
    const int w0 = q0 - 128;

    const int lr = tid >> 2;
    const int ld = (tid & 3) * 16;

    #pragma unroll
    for (int t = 0; t < 4; ++t) {
        float4 v4 = *(const float4*)&q[(size_t)(q0 + lr) * 512 + h * 64 + ld + t * 4];
        Qs[ld + t * 4 + 0][lr] = v4.x;
        Qs[ld + t * 4 + 1][lr] = v4.y;
        Qs[ld + t * 4 + 2][lr] = v4.z;
        Qs[ld + t * 4 + 3][lr] = v4.w;
    }

    const int rr = (tid & 15) * 4;
    const int cc = (tid >> 4) * 4;

    for (int ch = 0; ch < 5; ++ch) {
        const int c0 = w0 + ch * 64;
        if (c0 < 0 || c0 >= S) continue;
        __syncthreads();
        #pragma unroll
        for (int t = 0; t < 4; ++t) {
            float4 v4 = *(const float4*)&k[(size_t)(c0 + lr) * 512 + h * 64 + ld + t * 4];
            Ks[ld + t * 4 + 0][lr] = v4.x;
            Ks[ld + t * 4 + 1][lr] = v4.y;
            Ks[ld + t * 4 + 2][lr] = v4.z;
            Ks[ld + t * 4 + 3][lr] = v4.w;
        }
        __syncthreads();

        float sc[4][4] = {};
        #pragma unroll 8
        for (int d = 0; d < 64; ++d) {
            float4 qv = *(const float4*)&Qs[d][rr];
            float4 kv = *(const float4*)&Ks[d][cc];
            const float qa[4] = {qv.x, qv.y, qv.z, qv.w};
            const float ka[4] = {kv.x, kv.y, kv.z, kv.w};
            #pragma unroll
            for (int i = 0; i < 4; ++i)
                #pragma unroll
                for (int j = 0; j < 4; ++j)
                    sc[i][j] = fmaf(qa[i], ka[j], sc[i][j]);
        }

        #pragma unroll
        for (int i = 0; i < 4; ++i) {
            float4 o = {sc[i][0] * 0.125f, sc[i][1] * 0.125f,
                        sc[i][2] * 0.125f, sc[i][3] * 0.125f};
            *(float4*)&P[rr + i][ch * 64 + cc] = o;
        }
    }
    __syncthreads();

    {
        const int r  = tid >> 2;
        const int l2 = tid & 3;
        const int i  = q0 + r;
        const int lo = max(i - WIN, 0) - w0;
        const int hi = min(i + WIN, S - 1) - w0;

        float m = -1e30f;
        for (int c = lo + l2; c <= hi; c += 4) m = fmaxf(m, P[r][c]);
        m = fmaxf(m, __shfl_xor(m, 1));
        m = fmaxf(m, __shfl_xor(m, 2));

        float sum = 0.f;
        for (int c = lo + l2; c <= hi; c += 4) {
            float e = __expf(P[r][c] - m);
            P[r][c] = e;
            sum += e;
        }
        sum += __shfl_xor(sum, 1);
        sum += __shfl_xor(sum, 2);
        if (l2 == 0) rinvs[r] = 1.0f / sum;
    }
    __syncthreads();

    // ---- write band windows: 64 rows x 68 float4 slots = 17 iterations ----
    float* rowbase = attn + (size_t)h * S * S;
    #pragma unroll 1
    for (int it = 0; it < 17; ++it) {
        const int slot = it * 256 + tid;
        const int r = (int)((unsigned)slot / 68u);
        const int j = slot - r * 68;
        const int i = q0 + r;
        const int start = max(i - WIN, 0) & ~3;
        const int col = start + j * 4;
        if (col < S) {
            const int lo = max(i - WIN, 0) - w0;
            const int hi = min(i + WIN, S - 1) - w0;
            const int lc = col - w0;
            const float rv = rinvs[r];
            float4 o;
            if (lc >= lo && lc + 3 <= hi) {
                float4 p = *(const float4*)&P[r][lc];
                o.x = p.x * rv; o.y = p.y * rv; o.z = p.z * rv; o.w = p.w * rv;
            } else {
                o.x = (lc + 0 >= lo && lc + 0 <= hi) ? P[r][lc + 0] * rv : 0.f;
                o.y = (lc + 1 >= lo && lc + 1 <= hi) ? P[r][lc + 1] * rv : 0.f;
                o.z = (lc + 2 >= lo && lc + 2 <= hi) ? P[r][lc + 2] * rv : 0.f;
                o.w = (lc + 3 >= lo && lc + 3 <= hi) ? P[r][lc + 3] * rv : 0.f;
            }
            *(float4*)&rowbase[(size_t)i * S + col] = o;
        }
    }
}

// ---------------------------------------------------------------------------
// PV via MFMA: ctx[64][64] = P[64][320] x V[320][64] per (q-block, head).
// P read from attn (fp32 -> bf16), V transposed into LDS as bf16.
// ---------------------------------------------------------------------------
__global__ __launch_bounds__(256) void band_pv_kernel(
    const float* __restrict__ attn, const float* __restrict__ v,
    unsigned short* __restrict__ ctxb)
{
    __shared__ unsigned short Pb [64][328];   // Pb[row][local col]
    __shared__ unsigned short VsT[64][328];   // VsT[d][local col]
    const int tid = threadIdx.x;
    const int h  = blockIdx.y;
    const int q0 = blockIdx.x * 64;
    const int w0 = q0 - 128;

    const int lr = tid >> 2;           // 0..63
    const int ld = (tid & 3) * 16;     // 0,16,32,48
    const float* aptr = attn + (size_t)h * S * S;

    for (int ch = 0; ch < 5; ++ch) {
        const int c0 = w0 + ch * 64;
        if (c0 >= 0 && c0 < S) {
            #pragma unroll
            for (int t = 0; t < 4; ++t) {
                float4 p4 = *(const float4*)&aptr[(size_t)(q0 + lr) * S + c0 + ld + t * 4];
                ushort4 o = {f2bf(p4.x), f2bf(p4.y), f2bf(p4.z), f2bf(p4.w)};
                *(ushort4*)&Pb[lr][ch * 64 + ld + t * 4] = o;
                float4 v4 = *(const float4*)&v[(size_t)(c0 + lr) * 512 + h * 64 + ld + t * 4];
                VsT[ld + t * 4 + 0][ch * 64 + lr] = f2bf(v4.x);
                VsT[ld + t * 4 + 1][ch * 64 + lr] = f2bf(v4.y);
                VsT[ld + t * 4 + 2][ch * 64 + lr] = f2bf(v4.z);
                VsT[ld + t * 4 + 3][ch * 64 + lr] = f2bf(v4.w);
            }
        } else {
            #pragma unroll
            for (int t = 0; t < 4; ++t) {
                ushort4 z4 = {0, 0, 0, 0};
                *(ushort4*)&Pb[lr][ch * 64 + ld + t * 4] = z4;
                VsT[ld + t * 4 + 0][ch * 64 + lr] = 0;
                VsT[ld + t * 4 + 1][ch * 64 + lr] = 0;
                VsT[ld + t * 4 + 2][ch * 64 + lr] = 0;
                VsT[ld + t * 4 + 3][ch * 64 + lr] = 0;
            }
        }
    }
    __syncthreads();

    const int wv   = tid >> 6;
    const int lane = tid & 63;
    const int l16  = lane & 15;
    const int klo  = (lane >> 4) * 8;

    f32x4 acc[4];
    #pragma unroll
    for (int nf = 0; nf < 4; ++nf) acc[nf] = (f32x4){0.f, 0.f, 0.f, 0.f};

    #pragma unroll
    for (int ks = 0; ks < 10; ++ks) {
        bf16x8 a = *(const bf16x8*)&Pb[wv * 16 + l16][ks * 32 + klo];
        #pragma unroll
        for (int nf = 0; nf < 4; ++nf) {
            bf16x8 b = *(const bf16x8*)&VsT[nf * 16 + l16][ks * 32 + klo];
            acc[nf] = __builtin_amdgcn_mfma_f32_16x16x32_bf16(a, b, acc[nf], 0, 0, 0);
        }
    }

    const int r0 = (lane >> 4) * 4;
    #pragma unroll
    for (int nf = 0; nf < 4; ++nf) {
        #pragma unroll
        for (int vv = 0; vv < 4; ++vv) {
            const int row = q0 + wv * 16 + r0 + vv;
            ctxb[(size_t)row * 512 + h * 64 + nf * 16 + l16] = f2bf(acc[nf][vv]);
        }
    }
}

// ---------------------------------------------------------------------------
extern "C" void kernel_launch(void* const* d_in, const int* in_sizes, int n_in,
                              void* d_out, int out_size, void* d_ws, size_t ws_size,
                              hipStream_t stream)
{
    (void)in_sizes; (void)n_in; (void)out_size; (void)ws_size;
    const float* x  = (const float*)d_in[0];
    const float* wq = (const float*)d_in[1];
    const float* bq = (const float*)d_in[2];
    const float* wk = (const float*)d_in[3];
    const float* bk = (const float*)d_in[4];
    const float* wv = (const float*)d_in[5];
    const float* bv = (const float*)d_in[6];
    const float* wo = (const float*)d_in[7];
    const float* bo = (const float*)d_in[8];

    float* out  = (float*)d_out;                       // (S, D)
    float* attn = out + (size_t)S * D;                 // (H, S, S)

    float* q = (float*)d_ws;                           // 8 MB each
    float* k = q + (size_t)S * D;
    float* v = k + (size_t)S * D;
    unsigned short* xb   = (unsigned short*)(v + (size_t)S * D);  // 4 MB
    unsigned short* ctxb = xb + (size_t)S * D;                    // 4 MB

    conv_bf16_kernel<<<(S * D) / (256 * 8), 256, 0, stream>>>(x, xb, S * D);
    attn_fill_kernel<<<4096, 256, 0, stream>>>(attn);
    proj3_kernel<<<dim3(32, 8, 3), 256, 0, stream>>>(xb, wq, bq, wk, bk, wv, bv, q, k, v);
    band_attn_kernel<<<dim3(64, 8), 256, 0, stream>>>(q, k, attn);
    band_pv_kernel<<<dim3(64, 8), 256, 0, stream>>>(attn, v, ctxb);
    outproj_kernel<<<dim3(32, 8), 256, 0, stream>>>(ctxb, wo, bo, out);
}